// Round 1
// baseline (930.542 us; speedup 1.0000x reference)
//
#include <hip/hip_runtime.h>
#include <math.h>

#define D 128
#define NND 50000
#define NE 800000
#define TE 16   // edges per block (edge kernel)
#define TN 16   // nodes per block (precompute / node kernels)

__device__ __forceinline__ float silu_f(float v) {
    return v / (1.0f + __expf(-v));
}

// ---------------- zero workspace (agg) ----------------
__global__ void zero_kernel(float4* __restrict__ p, int n4) {
    int i = blockIdx.x * blockDim.x + threadIdx.x;
    float4 z = make_float4(0.f, 0.f, 0.f, 0.f);
    for (; i < n4; i += gridDim.x * blockDim.x) p[i] = z;
}

// ---------------- A = x @ W1e[0:128], B = x @ W1e[128:256] ----------------
__global__ void precompute_kernel(const float* __restrict__ x,
                                  const float* __restrict__ W1e,
                                  float* __restrict__ A,
                                  float* __restrict__ Bm) {
    __shared__ float xs[TN][D];
    const int j = threadIdx.x;            // 0..127
    const int n0 = blockIdx.x * TN;

    #pragma unroll
    for (int i = 0; i < TN; ++i) {
        int n = n0 + i;
        xs[i][j] = (n < NND) ? x[n * D + j] : 0.f;
    }
    __syncthreads();

    float accA[TN], accB[TN];
    #pragma unroll
    for (int i = 0; i < TN; ++i) { accA[i] = 0.f; accB[i] = 0.f; }

    for (int k4 = 0; k4 < D / 4; ++k4) {
        const int k = 4 * k4;
        float wa0 = W1e[(k + 0) * D + j];
        float wa1 = W1e[(k + 1) * D + j];
        float wa2 = W1e[(k + 2) * D + j];
        float wa3 = W1e[(k + 3) * D + j];
        float wb0 = W1e[(D + k + 0) * D + j];
        float wb1 = W1e[(D + k + 1) * D + j];
        float wb2 = W1e[(D + k + 2) * D + j];
        float wb3 = W1e[(D + k + 3) * D + j];
        #pragma unroll
        for (int i = 0; i < TN; ++i) {
            float4 v = ((const float4*)xs[i])[k4];
            accA[i] = fmaf(v.x, wa0, accA[i]);
            accA[i] = fmaf(v.y, wa1, accA[i]);
            accA[i] = fmaf(v.z, wa2, accA[i]);
            accA[i] = fmaf(v.w, wa3, accA[i]);
            accB[i] = fmaf(v.x, wb0, accB[i]);
            accB[i] = fmaf(v.y, wb1, accB[i]);
            accB[i] = fmaf(v.z, wb2, accB[i]);
            accB[i] = fmaf(v.w, wb3, accB[i]);
        }
    }
    #pragma unroll
    for (int i = 0; i < TN; ++i) {
        int n = n0 + i;
        if (n < NND) { A[n * D + j] = accA[i]; Bm[n * D + j] = accB[i]; }
    }
}

// ---------------- edge MLP + scatter-add ----------------
__global__ void edge_kernel(const float* __restrict__ A,
                            const float* __restrict__ Bm,
                            const float* __restrict__ pos,
                            const int* __restrict__ ei,
                            const float* __restrict__ W1e,
                            const float* __restrict__ b1e,
                            const float* __restrict__ W2e,
                            const float* __restrict__ b2e,
                            float* __restrict__ agg) {
    __shared__ float hs[TE][D];
    __shared__ int er[TE];
    __shared__ int ec[TE];
    __shared__ float ed2[TE];

    const int j = threadIdx.x;            // 0..127
    const int e0 = blockIdx.x * TE;

    if (j < TE) {
        int e = e0 + j;
        int r = 0, c = 0; float d2 = 0.f;
        if (e < NE) {
            r = ei[e];
            c = ei[NE + e];
            float dx = pos[r * 3 + 0] - pos[c * 3 + 0];
            float dy = pos[r * 3 + 1] - pos[c * 3 + 1];
            float dz = pos[r * 3 + 2] - pos[c * 3 + 2];
            d2 = dx * dx + dy * dy + dz * dz;
        }
        er[j] = r; ec[j] = c; ed2[j] = d2;
    }
    __syncthreads();

    const float wl  = W1e[256 * D + j];   // last row of W1e (dist2 term)
    const float bb1 = b1e[j];

    // layer 1: h = silu(A[row] + B[col] + dist2*wl + b1)
    #pragma unroll 4
    for (int i = 0; i < TE; ++i) {
        int e = e0 + i;
        float v = 0.f;
        if (e < NE) {
            float a = A[er[i] * D + j];
            float b = Bm[ec[i] * D + j];
            v = silu_f(fmaf(ed2[i], wl, a + b + bb1));
        }
        hs[i][j] = v;
    }
    __syncthreads();

    // layer 2: ef = silu(h @ W2e + b2)
    float acc[TE];
    const float bb2 = b2e[j];
    #pragma unroll
    for (int i = 0; i < TE; ++i) acc[i] = bb2;

    for (int k4 = 0; k4 < D / 4; ++k4) {
        const int k = 4 * k4;
        float w0 = W2e[(k + 0) * D + j];
        float w1 = W2e[(k + 1) * D + j];
        float w2 = W2e[(k + 2) * D + j];
        float w3 = W2e[(k + 3) * D + j];
        #pragma unroll
        for (int i = 0; i < TE; ++i) {
            float4 h4 = ((const float4*)hs[i])[k4];
            acc[i] = fmaf(h4.x, w0, acc[i]);
            acc[i] = fmaf(h4.y, w1, acc[i]);
            acc[i] = fmaf(h4.z, w2, acc[i]);
            acc[i] = fmaf(h4.w, w3, acc[i]);
        }
    }

    #pragma unroll
    for (int i = 0; i < TE; ++i) {
        int e = e0 + i;
        if (e < NE) {
            atomicAdd(&agg[er[i] * D + j], silu_f(acc[i]));
        }
    }
}

// ---------------- node MLP + residual + LayerNorm ----------------
__global__ void node_kernel(const float* __restrict__ x,
                            const float* __restrict__ agg,
                            const float* __restrict__ W1n,
                            const float* __restrict__ b1n,
                            const float* __restrict__ W2n,
                            const float* __restrict__ b2n,
                            const float* __restrict__ gamma,
                            const float* __restrict__ beta,
                            float* __restrict__ out) {
    __shared__ float xs[TN][D];
    __shared__ float gs[TN][D];
    __shared__ float ts[TN][D];
    __shared__ float ys[TN][D];
    __shared__ float mus[TN], rsd[TN];

    const int j = threadIdx.x;            // 0..127
    const int n0 = blockIdx.x * TN;

    #pragma unroll
    for (int i = 0; i < TN; ++i) {
        int n = n0 + i;
        xs[i][j] = (n < NND) ? x[n * D + j] : 0.f;
        gs[i][j] = (n < NND) ? agg[n * D + j] : 0.f;
    }
    __syncthreads();

    // layer 1: t = silu([x, agg] @ W1n + b1n)
    float acc[TN];
    const float bb1 = b1n[j];
    #pragma unroll
    for (int i = 0; i < TN; ++i) acc[i] = bb1;

    for (int k4 = 0; k4 < D / 4; ++k4) {
        const int k = 4 * k4;
        float w0 = W1n[(k + 0) * D + j];
        float w1 = W1n[(k + 1) * D + j];
        float w2 = W1n[(k + 2) * D + j];
        float w3 = W1n[(k + 3) * D + j];
        #pragma unroll
        for (int i = 0; i < TN; ++i) {
            float4 v = ((const float4*)xs[i])[k4];
            acc[i] = fmaf(v.x, w0, acc[i]);
            acc[i] = fmaf(v.y, w1, acc[i]);
            acc[i] = fmaf(v.z, w2, acc[i]);
            acc[i] = fmaf(v.w, w3, acc[i]);
        }
    }
    for (int k4 = 0; k4 < D / 4; ++k4) {
        const int k = 4 * k4;
        float w0 = W1n[(D + k + 0) * D + j];
        float w1 = W1n[(D + k + 1) * D + j];
        float w2 = W1n[(D + k + 2) * D + j];
        float w3 = W1n[(D + k + 3) * D + j];
        #pragma unroll
        for (int i = 0; i < TN; ++i) {
            float4 v = ((const float4*)gs[i])[k4];
            acc[i] = fmaf(v.x, w0, acc[i]);
            acc[i] = fmaf(v.y, w1, acc[i]);
            acc[i] = fmaf(v.z, w2, acc[i]);
            acc[i] = fmaf(v.w, w3, acc[i]);
        }
    }
    #pragma unroll
    for (int i = 0; i < TN; ++i) ts[i][j] = silu_f(acc[i]);
    __syncthreads();

    // layer 2: u = t @ W2n + b2n ; y = x + u
    float acc2[TN];
    const float bb2 = b2n[j];
    #pragma unroll
    for (int i = 0; i < TN; ++i) acc2[i] = bb2;

    for (int k4 = 0; k4 < D / 4; ++k4) {
        const int k = 4 * k4;
        float w0 = W2n[(k + 0) * D + j];
        float w1 = W2n[(k + 1) * D + j];
        float w2 = W2n[(k + 2) * D + j];
        float w3 = W2n[(k + 3) * D + j];
        #pragma unroll
        for (int i = 0; i < TN; ++i) {
            float4 t4 = ((const float4*)ts[i])[k4];
            acc2[i] = fmaf(t4.x, w0, acc2[i]);
            acc2[i] = fmaf(t4.y, w1, acc2[i]);
            acc2[i] = fmaf(t4.z, w2, acc2[i]);
            acc2[i] = fmaf(t4.w, w3, acc2[i]);
        }
    }
    #pragma unroll
    for (int i = 0; i < TN; ++i) ys[i][j] = xs[i][j] + acc2[i];
    __syncthreads();

    // LayerNorm: per-node mean/var via wave shuffle (wave handles alternate nodes)
    const int wave = j >> 6;
    const int lane = j & 63;
    for (int i = wave; i < TN; i += 2) {
        float a = ys[i][lane];
        float b = ys[i][lane + 64];
        float s  = a + b;
        float s2 = a * a + b * b;
        #pragma unroll
        for (int off = 32; off > 0; off >>= 1) {
            s  += __shfl_down(s, off);
            s2 += __shfl_down(s2, off);
        }
        if (lane == 0) {
            float mu  = s * (1.f / 128.f);
            float var = s2 * (1.f / 128.f) - mu * mu;
            mus[i] = mu;
            rsd[i] = rsqrtf(var + 1e-5f);
        }
    }
    __syncthreads();

    const float g  = gamma[j];
    const float bt = beta[j];
    #pragma unroll
    for (int i = 0; i < TN; ++i) {
        int n = n0 + i;
        if (n < NND) out[n * D + j] = (ys[i][j] - mus[i]) * rsd[i] * g + bt;
    }
}

extern "C" void kernel_launch(void* const* d_in, const int* in_sizes, int n_in,
                              void* d_out, int out_size, void* d_ws, size_t ws_size,
                              hipStream_t stream) {
    const float* x     = (const float*)d_in[0];
    const float* pos   = (const float*)d_in[1];
    const int*   ei    = (const int*)d_in[2];
    const float* W1e   = (const float*)d_in[3];
    const float* b1e   = (const float*)d_in[4];
    const float* W2e   = (const float*)d_in[5];
    const float* b2e   = (const float*)d_in[6];
    const float* W1n   = (const float*)d_in[7];
    const float* b1n   = (const float*)d_in[8];
    const float* W2n   = (const float*)d_in[9];
    const float* b2n   = (const float*)d_in[10];
    const float* gamma = (const float*)d_in[11];
    const float* beta  = (const float*)d_in[12];
    float* out = (float*)d_out;

    // workspace layout: A [N*D] | B [N*D] | agg [N*D]   (76.8 MB total, fp32)
    float* A   = (float*)d_ws;
    float* Bm  = A + (size_t)NND * D;
    float* agg = Bm + (size_t)NND * D;

    // zero agg (ws is poisoned each call)
    zero_kernel<<<2048, 256, 0, stream>>>((float4*)agg, NND * D / 4);

    // A/B precompute: factored edge layer-1 GEMMs over nodes
    precompute_kernel<<<(NND + TN - 1) / TN, D, 0, stream>>>(x, W1e, A, Bm);

    // edge MLP + scatter
    edge_kernel<<<(NE + TE - 1) / TE, D, 0, stream>>>(A, Bm, pos, ei, W1e, b1e,
                                                      W2e, b2e, agg);

    // node MLP + residual + LN
    node_kernel<<<(NND + TN - 1) / TN, D, 0, stream>>>(x, agg, W1n, b1n, W2n, b2n,
                                                       gamma, beta, out);
}

// Round 2
// 679.282 us; speedup vs baseline: 1.3699x; 1.3699x over previous
//
#include <hip/hip_runtime.h>
#include <math.h>

#define D 128
#define NND 50000
#define NE 800000
#define TN 16          // nodes per block (precompute / node kernels)
#define TEB 64         // edges per block (edge kernel)
#define HS_PITCH 136   // ushorts per LDS row: 128 + 8 pad (272 B, breaks bank stride)

typedef __attribute__((ext_vector_type(8))) short shortx8;
typedef __attribute__((ext_vector_type(4))) float floatx4;

__device__ __forceinline__ float silu_f(float v) {
    return v / (1.0f + __expf(-v));
}
__device__ __forceinline__ unsigned short f2bf(float f) {
    union { float f; unsigned int u; } v; v.f = f;
    unsigned int u = v.u;
    u += 0x7fffu + ((u >> 16) & 1u);   // RNE
    return (unsigned short)(u >> 16);
}
__device__ __forceinline__ float bf2f(unsigned int hbits) {
    union { unsigned int u; float f; } v; v.u = hbits << 16;
    return v.f;
}

// ---------------- zero workspace (agg) ----------------
__global__ void zero_kernel(float4* __restrict__ p, int n4) {
    int i = blockIdx.x * blockDim.x + threadIdx.x;
    float4 z = make_float4(0.f, 0.f, 0.f, 0.f);
    for (; i < n4; i += gridDim.x * blockDim.x) p[i] = z;
}

// ---------------- W2eT[n][k] = bf16(W2e[k][n]) ----------------
__global__ void w2et_kernel(const float* __restrict__ W2e,
                            unsigned short* __restrict__ W2eT) {
    int idx = blockIdx.x * 256 + threadIdx.x;   // 16384 total
    int n = idx >> 7, k = idx & 127;
    W2eT[idx] = f2bf(W2e[k * D + n]);
}

// ---------------- A = bf16(x @ W1e[0:128]), B = bf16(x @ W1e[128:256]) ----------------
__global__ void precompute_kernel(const float* __restrict__ x,
                                  const float* __restrict__ W1e,
                                  unsigned short* __restrict__ A,
                                  unsigned short* __restrict__ Bm) {
    __shared__ float xs[TN][D];
    const int j = threadIdx.x;            // 0..127
    const int n0 = blockIdx.x * TN;

    #pragma unroll
    for (int i = 0; i < TN; ++i) {
        int n = n0 + i;
        xs[i][j] = (n < NND) ? x[n * D + j] : 0.f;
    }
    __syncthreads();

    float accA[TN], accB[TN];
    #pragma unroll
    for (int i = 0; i < TN; ++i) { accA[i] = 0.f; accB[i] = 0.f; }

    for (int k4 = 0; k4 < D / 4; ++k4) {
        const int k = 4 * k4;
        float wa0 = W1e[(k + 0) * D + j];
        float wa1 = W1e[(k + 1) * D + j];
        float wa2 = W1e[(k + 2) * D + j];
        float wa3 = W1e[(k + 3) * D + j];
        float wb0 = W1e[(D + k + 0) * D + j];
        float wb1 = W1e[(D + k + 1) * D + j];
        float wb2 = W1e[(D + k + 2) * D + j];
        float wb3 = W1e[(D + k + 3) * D + j];
        #pragma unroll
        for (int i = 0; i < TN; ++i) {
            float4 v = ((const float4*)xs[i])[k4];
            accA[i] = fmaf(v.x, wa0, accA[i]);
            accA[i] = fmaf(v.y, wa1, accA[i]);
            accA[i] = fmaf(v.z, wa2, accA[i]);
            accA[i] = fmaf(v.w, wa3, accA[i]);
            accB[i] = fmaf(v.x, wb0, accB[i]);
            accB[i] = fmaf(v.y, wb1, accB[i]);
            accB[i] = fmaf(v.z, wb2, accB[i]);
            accB[i] = fmaf(v.w, wb3, accB[i]);
        }
    }
    #pragma unroll
    for (int i = 0; i < TN; ++i) {
        int n = n0 + i;
        if (n < NND) {
            A[n * D + j]  = f2bf(accA[i]);
            Bm[n * D + j] = f2bf(accB[i]);
        }
    }
}

// ---------------- edge MLP (MFMA layer 2) + scatter-add ----------------
// 64 edges/block, 4 waves; wave w owns edges [16w, 16w+16).
// NE = 800000 = 12500 * 64 exactly -> no bounds checks.
__global__ __launch_bounds__(256) void edge_kernel(
        const unsigned short* __restrict__ Abf,
        const unsigned short* __restrict__ Bbf,
        const float* __restrict__ pos,
        const int* __restrict__ ei,
        const float* __restrict__ W1e,
        const float* __restrict__ b1e,
        const unsigned short* __restrict__ W2eT,
        const float* __restrict__ b2e,
        float* __restrict__ agg) {
    __shared__ __align__(16) unsigned short w2s[128 * HS_PITCH]; // 34816 B
    __shared__ __align__(16) unsigned short hs[TEB * HS_PITCH];  // 17408 B
    __shared__ int   ser[TEB];
    __shared__ int   sec[TEB];
    __shared__ float sd2[TEB];

    const int t    = threadIdx.x;
    const int wv   = t >> 6;
    const int lane = t & 63;
    const int e0   = blockIdx.x * TEB;

    // stage W2eT (bf16 [n][k]) into LDS with padded pitch
    {
        const float4* g = (const float4*)W2eT;   // 2048 float4
        #pragma unroll
        for (int i = 0; i < 8; ++i) {
            int idx = t + i * 256;
            int n = idx >> 4, q = idx & 15;
            *(float4*)((char*)w2s + n * (HS_PITCH * 2) + q * 16) = g[idx];
        }
    }
    // per-edge metadata (wave-local rows)
    if (lane < 16) {
        int e = e0 + wv * 16 + lane;
        int r = ei[e], c = ei[NE + e];
        float dx = pos[r * 3 + 0] - pos[c * 3 + 0];
        float dy = pos[r * 3 + 1] - pos[c * 3 + 1];
        float dz = pos[r * 3 + 2] - pos[c * 3 + 2];
        ser[wv * 16 + lane] = r;
        sec[wv * 16 + lane] = c;
        sd2[wv * 16 + lane] = dx * dx + dy * dy + dz * dz;
    }
    __syncthreads();   // w2s visible to all waves (meta/hs are wave-local)

    // phase 1: h = silu(A[row] + B[col] + dist2*wl + b1), bf16 into hs
    const int   c0  = lane * 2;                      // column pair
    const float wl0 = W1e[256 * D + c0];
    const float wl1 = W1e[256 * D + c0 + 1];
    const float bb0 = b1e[c0];
    const float bb1 = b1e[c0 + 1];
    #pragma unroll
    for (int i = 0; i < 16; ++i) {
        int m = wv * 16 + i;
        int r = ser[m], c = sec[m];
        float d2 = sd2[m];
        unsigned int a2 = ((const unsigned int*)Abf)[r * (D / 2) + lane];
        unsigned int b2 = ((const unsigned int*)Bbf)[c * (D / 2) + lane];
        float a0 = bf2f(a2 & 0xffffu), a1 = bf2f(a2 >> 16);
        float q0 = bf2f(b2 & 0xffffu), q1 = bf2f(b2 >> 16);
        float v0 = silu_f(fmaf(d2, wl0, a0 + q0 + bb0));
        float v1 = silu_f(fmaf(d2, wl1, a1 + q1 + bb1));
        unsigned int packed = (unsigned int)f2bf(v0) | ((unsigned int)f2bf(v1) << 16);
        *(unsigned int*)((char*)hs + m * (HS_PITCH * 2) + lane * 4) = packed;
    }

    // phase 2: [16 edges x 128] @ [128 x 128] via 16x16x32 bf16 MFMA
    const int mrow = lane & 15;   // A: m-row / B: n-col / C: col
    const int quad = lane >> 4;   // k-group select; C: row = quad*4+reg
    floatx4 acc[8];
    #pragma unroll
    for (int n = 0; n < 8; ++n) {
        float b = b2e[n * 16 + mrow];
        acc[n] = (floatx4){b, b, b, b};
    }
    #pragma unroll
    for (int s = 0; s < 4; ++s) {
        const int koff = (s * 32 + quad * 8) * 2;   // bytes, 16B-aligned
        shortx8 af = *(const shortx8*)((const char*)hs +
                        (wv * 16 + mrow) * (HS_PITCH * 2) + koff);
        #pragma unroll
        for (int n = 0; n < 8; ++n) {
            shortx8 bf = *(const shortx8*)((const char*)w2s +
                            (n * 16 + mrow) * (HS_PITCH * 2) + koff);
            acc[n] = __builtin_amdgcn_mfma_f32_16x16x32_bf16(af, bf, acc[n], 0, 0, 0);
        }
    }

    // epilogue: silu + scatter atomicAdd
    #pragma unroll
    for (int reg = 0; reg < 4; ++reg) {
        int m = wv * 16 + quad * 4 + reg;
        float* dst = agg + (size_t)ser[m] * D;
        #pragma unroll
        for (int n = 0; n < 8; ++n) {
            atomicAdd(dst + n * 16 + mrow, silu_f(acc[n][reg]));
        }
    }
}

// ---------------- node MLP + residual + LayerNorm ----------------
__global__ void node_kernel(const float* __restrict__ x,
                            const float* __restrict__ agg,
                            const float* __restrict__ W1n,
                            const float* __restrict__ b1n,
                            const float* __restrict__ W2n,
                            const float* __restrict__ b2n,
                            const float* __restrict__ gamma,
                            const float* __restrict__ beta,
                            float* __restrict__ out) {
    __shared__ float xs[TN][D];
    __shared__ float gs[TN][D];
    __shared__ float ts[TN][D];
    __shared__ float ys[TN][D];
    __shared__ float mus[TN], rsd[TN];

    const int j = threadIdx.x;            // 0..127
    const int n0 = blockIdx.x * TN;

    #pragma unroll
    for (int i = 0; i < TN; ++i) {
        int n = n0 + i;
        xs[i][j] = (n < NND) ? x[n * D + j] : 0.f;
        gs[i][j] = (n < NND) ? agg[n * D + j] : 0.f;
    }
    __syncthreads();

    float acc[TN];
    const float bb1 = b1n[j];
    #pragma unroll
    for (int i = 0; i < TN; ++i) acc[i] = bb1;

    for (int k4 = 0; k4 < D / 4; ++k4) {
        const int k = 4 * k4;
        float w0 = W1n[(k + 0) * D + j];
        float w1 = W1n[(k + 1) * D + j];
        float w2 = W1n[(k + 2) * D + j];
        float w3 = W1n[(k + 3) * D + j];
        #pragma unroll
        for (int i = 0; i < TN; ++i) {
            float4 v = ((const float4*)xs[i])[k4];
            acc[i] = fmaf(v.x, w0, acc[i]);
            acc[i] = fmaf(v.y, w1, acc[i]);
            acc[i] = fmaf(v.z, w2, acc[i]);
            acc[i] = fmaf(v.w, w3, acc[i]);
        }
    }
    for (int k4 = 0; k4 < D / 4; ++k4) {
        const int k = 4 * k4;
        float w0 = W1n[(D + k + 0) * D + j];
        float w1 = W1n[(D + k + 1) * D + j];
        float w2 = W1n[(D + k + 2) * D + j];
        float w3 = W1n[(D + k + 3) * D + j];
        #pragma unroll
        for (int i = 0; i < TN; ++i) {
            float4 v = ((const float4*)gs[i])[k4];
            acc[i] = fmaf(v.x, w0, acc[i]);
            acc[i] = fmaf(v.y, w1, acc[i]);
            acc[i] = fmaf(v.z, w2, acc[i]);
            acc[i] = fmaf(v.w, w3, acc[i]);
        }
    }
    #pragma unroll
    for (int i = 0; i < TN; ++i) ts[i][j] = silu_f(acc[i]);
    __syncthreads();

    float acc2[TN];
    const float bb2 = b2n[j];
    #pragma unroll
    for (int i = 0; i < TN; ++i) acc2[i] = bb2;

    for (int k4 = 0; k4 < D / 4; ++k4) {
        const int k = 4 * k4;
        float w0 = W2n[(k + 0) * D + j];
        float w1 = W2n[(k + 1) * D + j];
        float w2 = W2n[(k + 2) * D + j];
        float w3 = W2n[(k + 3) * D + j];
        #pragma unroll
        for (int i = 0; i < TN; ++i) {
            float4 t4 = ((const float4*)ts[i])[k4];
            acc2[i] = fmaf(t4.x, w0, acc2[i]);
            acc2[i] = fmaf(t4.y, w1, acc2[i]);
            acc2[i] = fmaf(t4.z, w2, acc2[i]);
            acc2[i] = fmaf(t4.w, w3, acc2[i]);
        }
    }
    #pragma unroll
    for (int i = 0; i < TN; ++i) ys[i][j] = xs[i][j] + acc2[i];
    __syncthreads();

    const int wave = j >> 6;
    const int lane = j & 63;
    for (int i = wave; i < TN; i += 2) {
        float a = ys[i][lane];
        float b = ys[i][lane + 64];
        float s  = a + b;
        float s2 = a * a + b * b;
        #pragma unroll
        for (int off = 32; off > 0; off >>= 1) {
            s  += __shfl_down(s, off);
            s2 += __shfl_down(s2, off);
        }
        if (lane == 0) {
            float mu  = s * (1.f / 128.f);
            float var = s2 * (1.f / 128.f) - mu * mu;
            mus[i] = mu;
            rsd[i] = rsqrtf(var + 1e-5f);
        }
    }
    __syncthreads();

    const float g  = gamma[j];
    const float bt = beta[j];
    #pragma unroll
    for (int i = 0; i < TN; ++i) {
        int n = n0 + i;
        if (n < NND) out[n * D + j] = (ys[i][j] - mus[i]) * rsd[i] * g + bt;
    }
}

extern "C" void kernel_launch(void* const* d_in, const int* in_sizes, int n_in,
                              void* d_out, int out_size, void* d_ws, size_t ws_size,
                              hipStream_t stream) {
    const float* x     = (const float*)d_in[0];
    const float* pos   = (const float*)d_in[1];
    const int*   ei    = (const int*)d_in[2];
    const float* W1e   = (const float*)d_in[3];
    const float* b1e   = (const float*)d_in[4];
    const float* W2e   = (const float*)d_in[5];
    const float* b2e   = (const float*)d_in[6];
    const float* W1n   = (const float*)d_in[7];
    const float* b1n   = (const float*)d_in[8];
    const float* W2n   = (const float*)d_in[9];
    const float* b2n   = (const float*)d_in[10];
    const float* gamma = (const float*)d_in[11];
    const float* beta  = (const float*)d_in[12];
    float* out = (float*)d_out;

    // ws layout: Abf16 [N*D] | Bbf16 [N*D] | agg fp32 [N*D] | W2eT bf16 [D*D]
    unsigned short* Abf  = (unsigned short*)d_ws;
    unsigned short* Bbf  = Abf + (size_t)NND * D;
    float*          agg  = (float*)(Bbf + (size_t)NND * D);
    unsigned short* W2eT = (unsigned short*)(agg + (size_t)NND * D);

    zero_kernel<<<2048, 256, 0, stream>>>((float4*)agg, NND * D / 4);
    w2et_kernel<<<(D * D) / 256, 256, 0, stream>>>(W2e, W2eT);
    precompute_kernel<<<(NND + TN - 1) / TN, D, 0, stream>>>(x, W1e, Abf, Bbf);
    edge_kernel<<<NE / TEB, 256, 0, stream>>>(Abf, Bbf, pos, ei, W1e, b1e,
                                              W2eT, b2e, agg);
    node_kernel<<<(NND + TN - 1) / TN, D, 0, stream>>>(x, agg, W1n, b1n, W2n, b2n,
                                                       gamma, beta, out);
}

// Round 3
// 677.458 us; speedup vs baseline: 1.3736x; 1.0027x over previous
//
#include <hip/hip_runtime.h>
#include <hip/hip_bf16.h>
#include <math.h>

#define D 128
#define NND 50000
#define NE 800000
#define TN 16          // nodes per block (precompute / node kernels)

typedef __attribute__((ext_vector_type(8))) short shortx8;
typedef __attribute__((ext_vector_type(4))) float floatx4;

__device__ __forceinline__ float silu_f(float v) {
    return v / (1.0f + __expf(-v));
}
__device__ __forceinline__ unsigned short f2bf(float f) {
    union { float f; unsigned int u; } v; v.f = f;
    unsigned int u = v.u;
    u += 0x7fffu + ((u >> 16) & 1u);   // RNE
    return (unsigned short)(u >> 16);
}
// unpack packed bf16 pair (uint) -> two floats
__device__ __forceinline__ void unpk(unsigned int u, float& lo, float& hi) {
    union { unsigned int x; float f; } a, b;
    a.x = u << 16;
    b.x = u & 0xffff0000u;
    lo = a.f; hi = b.f;
}

// ---------------- zero workspace (agg) ----------------
__global__ void zero_kernel(float4* __restrict__ p, int n4) {
    int i = blockIdx.x * blockDim.x + threadIdx.x;
    float4 z = make_float4(0.f, 0.f, 0.f, 0.f);
    for (; i < n4; i += gridDim.x * blockDim.x) p[i] = z;
}

// ---------------- W2f: MFMA B-fragment swizzle of W2e ----------------
// W2f flat index f = (((s*4+quad)*128) + n*16 + mrow)*8 + j
//   = bf16(W2e[k][col]) with k = s*32+quad*8+j, col = n*16+mrow
__global__ void w2f_kernel(const float* __restrict__ W2e,
                           unsigned short* __restrict__ W2f) {
    int f = blockIdx.x * 256 + threadIdx.x;   // 16384 total
    int j    = f & 7;
    int mrow = (f >> 3) & 15;
    int n    = (f >> 7) & 7;
    int quad = (f >> 10) & 3;
    int s    = f >> 12;
    int col = n * 16 + mrow;
    int k   = s * 32 + quad * 8 + j;
    W2f[f] = f2bf(W2e[k * D + col]);
}

// ---------------- A = bf16(x @ W1e[0:128]), B = bf16(x @ W1e[128:256]) ----------------
__global__ void precompute_kernel(const float* __restrict__ x,
                                  const float* __restrict__ W1e,
                                  unsigned short* __restrict__ A,
                                  unsigned short* __restrict__ Bm) {
    __shared__ float xs[TN][D];
    const int j = threadIdx.x;            // 0..127
    const int n0 = blockIdx.x * TN;

    #pragma unroll
    for (int i = 0; i < TN; ++i) {
        int n = n0 + i;
        xs[i][j] = (n < NND) ? x[n * D + j] : 0.f;
    }
    __syncthreads();

    float accA[TN], accB[TN];
    #pragma unroll
    for (int i = 0; i < TN; ++i) { accA[i] = 0.f; accB[i] = 0.f; }

    for (int k4 = 0; k4 < D / 4; ++k4) {
        const int k = 4 * k4;
        float wa0 = W1e[(k + 0) * D + j];
        float wa1 = W1e[(k + 1) * D + j];
        float wa2 = W1e[(k + 2) * D + j];
        float wa3 = W1e[(k + 3) * D + j];
        float wb0 = W1e[(D + k + 0) * D + j];
        float wb1 = W1e[(D + k + 1) * D + j];
        float wb2 = W1e[(D + k + 2) * D + j];
        float wb3 = W1e[(D + k + 3) * D + j];
        #pragma unroll
        for (int i = 0; i < TN; ++i) {
            float4 v = ((const float4*)xs[i])[k4];
            accA[i] = fmaf(v.x, wa0, accA[i]);
            accA[i] = fmaf(v.y, wa1, accA[i]);
            accA[i] = fmaf(v.z, wa2, accA[i]);
            accA[i] = fmaf(v.w, wa3, accA[i]);
            accB[i] = fmaf(v.x, wb0, accB[i]);
            accB[i] = fmaf(v.y, wb1, accB[i]);
            accB[i] = fmaf(v.z, wb2, accB[i]);
            accB[i] = fmaf(v.w, wb3, accB[i]);
        }
    }
    #pragma unroll
    for (int i = 0; i < TN; ++i) {
        int n = n0 + i;
        if (n < NND) {
            A[n * D + j]  = f2bf(accA[i]);
            Bm[n * D + j] = f2bf(accB[i]);
        }
    }
}

// ---------------- edge MLP (LDS-free, barrier-free) ----------------
// 64 edges/block, 4 waves, 16 edges/wave. NE = 12500 * 64 exactly.
// Lane (mrow, quad) computes h[edge mrow][k = s*32+quad*8+0..7] in registers,
// feeds MFMA A-frag directly; B-frags stream from pre-swizzled W2f (L1/L2-hot).
__global__ __launch_bounds__(256, 4) void edge_kernel(
        const unsigned short* __restrict__ Abf,
        const unsigned short* __restrict__ Bbf,
        const float* __restrict__ pos,
        const int* __restrict__ ei,
        const float* __restrict__ W1e,
        const float* __restrict__ b1e,
        const unsigned short* __restrict__ W2f,
        const float* __restrict__ b2e,
        float* __restrict__ agg) {
    const int t    = threadIdx.x;
    const int wv   = t >> 6;
    const int lane = t & 63;
    const int mrow = lane & 15;
    const int quad = lane >> 4;

    // edge metadata: every lane loads its own edge (4x redundant across quads)
    const int e = blockIdx.x * 64 + wv * 16 + mrow;
    const int r = ei[e];
    const int c = ei[NE + e];
    float dx = pos[r * 3 + 0] - pos[c * 3 + 0];
    float dy = pos[r * 3 + 1] - pos[c * 3 + 1];
    float dz = pos[r * 3 + 2] - pos[c * 3 + 2];
    const float d2 = dx * dx + dy * dy + dz * dz;

    // accumulators: C[row=quad*4+reg][col=n*16+mrow], init with bias b2e[col]
    floatx4 acc[8];
    #pragma unroll
    for (int n = 0; n < 8; ++n) {
        float b = b2e[n * 16 + mrow];
        acc[n] = (floatx4){b, b, b, b};
    }

    const uint4*  arow = (const uint4*)(Abf + ((size_t)r << 7));   // 16 x uint4 per row
    const uint4*  brow = (const uint4*)(Bbf + ((size_t)c << 7));
    const float4* wlp  = (const float4*)(W1e + 256 * D);           // dist2 weight row
    const float4* b1p  = (const float4*)b1e;
    const uint4*  w2p  = (const uint4*)W2f;

    #pragma unroll
    for (int s = 0; s < 4; ++s) {
        // gather A/B chunks: 8 bf16 each (16 B/lane, coalesced per row segment)
        uint4 au = arow[s * 4 + quad];
        uint4 bu = brow[s * 4 + quad];
        float4 wlA = wlp[s * 8 + quad * 2];
        float4 wlB = wlp[s * 8 + quad * 2 + 1];
        float4 bbA = b1p[s * 8 + quad * 2];
        float4 bbB = b1p[s * 8 + quad * 2 + 1];

        float a0, a1, a2, a3, a4, a5, a6, a7;
        float q0, q1, q2, q3, q4, q5, q6, q7;
        unpk(au.x, a0, a1); unpk(au.y, a2, a3);
        unpk(au.z, a4, a5); unpk(au.w, a6, a7);
        unpk(bu.x, q0, q1); unpk(bu.y, q2, q3);
        unpk(bu.z, q4, q5); unpk(bu.w, q6, q7);

        float h0 = silu_f(fmaf(d2, wlA.x, a0 + q0 + bbA.x));
        float h1 = silu_f(fmaf(d2, wlA.y, a1 + q1 + bbA.y));
        float h2 = silu_f(fmaf(d2, wlA.z, a2 + q2 + bbA.z));
        float h3 = silu_f(fmaf(d2, wlA.w, a3 + q3 + bbA.w));
        float h4 = silu_f(fmaf(d2, wlB.x, a4 + q4 + bbB.x));
        float h5 = silu_f(fmaf(d2, wlB.y, a5 + q5 + bbB.y));
        float h6 = silu_f(fmaf(d2, wlB.z, a6 + q6 + bbB.z));
        float h7 = silu_f(fmaf(d2, wlB.w, a7 + q7 + bbB.w));

        // pack to bf16 A-fragment (v_cvt_pk_bf16_f32)
        union { shortx8 v; __hip_bfloat162 p[4]; } af;
        af.p[0] = __float22bfloat162_rn(float2{h0, h1});
        af.p[1] = __float22bfloat162_rn(float2{h2, h3});
        af.p[2] = __float22bfloat162_rn(float2{h4, h5});
        af.p[3] = __float22bfloat162_rn(float2{h6, h7});

        // 8 MFMAs, B-frags streamed from global (L1-hot 32 KB)
        const int base = (s * 4 + quad) * 128 + mrow;
        #pragma unroll
        for (int n = 0; n < 8; ++n) {
            union { uint4 u; shortx8 v; } bf;
            bf.u = w2p[base + n * 16];
            acc[n] = __builtin_amdgcn_mfma_f32_16x16x32_bf16(af.v, bf.v, acc[n], 0, 0, 0);
        }
    }

    // epilogue: silu + scatter atomicAdd. C row = quad*4+reg -> edge index
    #pragma unroll
    for (int reg = 0; reg < 4; ++reg) {
        int rr = __shfl(r, quad * 4 + reg);   // lanes 0-15 hold this wave's edges
        float* dst = agg + (size_t)rr * D;
        #pragma unroll
        for (int n = 0; n < 8; ++n) {
            atomicAdd(dst + n * 16 + mrow, silu_f(acc[n][reg]));
        }
    }
}

// ---------------- node MLP + residual + LayerNorm ----------------
__global__ void node_kernel(const float* __restrict__ x,
                            const float* __restrict__ agg,
                            const float* __restrict__ W1n,
                            const float* __restrict__ b1n,
                            const float* __restrict__ W2n,
                            const float* __restrict__ b2n,
                            const float* __restrict__ gamma,
                            const float* __restrict__ beta,
                            float* __restrict__ out) {
    __shared__ float xs[TN][D];
    __shared__ float gs[TN][D];
    __shared__ float ts[TN][D];
    __shared__ float ys[TN][D];
    __shared__ float mus[TN], rsd[TN];

    const int j = threadIdx.x;            // 0..127
    const int n0 = blockIdx.x * TN;

    #pragma unroll
    for (int i = 0; i < TN; ++i) {
        int n = n0 + i;
        xs[i][j] = (n < NND) ? x[n * D + j] : 0.f;
        gs[i][j] = (n < NND) ? agg[n * D + j] : 0.f;
    }
    __syncthreads();

    float acc[TN];
    const float bb1 = b1n[j];
    #pragma unroll
    for (int i = 0; i < TN; ++i) acc[i] = bb1;

    for (int k4 = 0; k4 < D / 4; ++k4) {
        const int k = 4 * k4;
        float w0 = W1n[(k + 0) * D + j];
        float w1 = W1n[(k + 1) * D + j];
        float w2 = W1n[(k + 2) * D + j];
        float w3 = W1n[(k + 3) * D + j];
        #pragma unroll
        for (int i = 0; i < TN; ++i) {
            float4 v = ((const float4*)xs[i])[k4];
            acc[i] = fmaf(v.x, w0, acc[i]);
            acc[i] = fmaf(v.y, w1, acc[i]);
            acc[i] = fmaf(v.z, w2, acc[i]);
            acc[i] = fmaf(v.w, w3, acc[i]);
        }
    }
    for (int k4 = 0; k4 < D / 4; ++k4) {
        const int k = 4 * k4;
        float w0 = W1n[(D + k + 0) * D + j];
        float w1 = W1n[(D + k + 1) * D + j];
        float w2 = W1n[(D + k + 2) * D + j];
        float w3 = W1n[(D + k + 3) * D + j];
        #pragma unroll
        for (int i = 0; i < TN; ++i) {
            float4 v = ((const float4*)gs[i])[k4];
            acc[i] = fmaf(v.x, w0, acc[i]);
            acc[i] = fmaf(v.y, w1, acc[i]);
            acc[i] = fmaf(v.z, w2, acc[i]);
            acc[i] = fmaf(v.w, w3, acc[i]);
        }
    }
    #pragma unroll
    for (int i = 0; i < TN; ++i) ts[i][j] = silu_f(acc[i]);
    __syncthreads();

    float acc2[TN];
    const float bb2 = b2n[j];
    #pragma unroll
    for (int i = 0; i < TN; ++i) acc2[i] = bb2;

    for (int k4 = 0; k4 < D / 4; ++k4) {
        const int k = 4 * k4;
        float w0 = W2n[(k + 0) * D + j];
        float w1 = W2n[(k + 1) * D + j];
        float w2 = W2n[(k + 2) * D + j];
        float w3 = W2n[(k + 3) * D + j];
        #pragma unroll
        for (int i = 0; i < TN; ++i) {
            float4 t4 = ((const float4*)ts[i])[k4];
            acc2[i] = fmaf(t4.x, w0, acc2[i]);
            acc2[i] = fmaf(t4.y, w1, acc2[i]);
            acc2[i] = fmaf(t4.z, w2, acc2[i]);
            acc2[i] = fmaf(t4.w, w3, acc2[i]);
        }
    }
    #pragma unroll
    for (int i = 0; i < TN; ++i) ys[i][j] = xs[i][j] + acc2[i];
    __syncthreads();

    const int wave = j >> 6;
    const int lane = j & 63;
    for (int i = wave; i < TN; i += 2) {
        float a = ys[i][lane];
        float b = ys[i][lane + 64];
        float s  = a + b;
        float s2 = a * a + b * b;
        #pragma unroll
        for (int off = 32; off > 0; off >>= 1) {
            s  += __shfl_down(s, off);
            s2 += __shfl_down(s2, off);
        }
        if (lane == 0) {
            float mu  = s * (1.f / 128.f);
            float var = s2 * (1.f / 128.f) - mu * mu;
            mus[i] = mu;
            rsd[i] = rsqrtf(var + 1e-5f);
        }
    }
    __syncthreads();

    const float g  = gamma[j];
    const float bt = beta[j];
    #pragma unroll
    for (int i = 0; i < TN; ++i) {
        int n = n0 + i;
        if (n < NND) out[n * D + j] = (ys[i][j] - mus[i]) * rsd[i] * g + bt;
    }
}

extern "C" void kernel_launch(void* const* d_in, const int* in_sizes, int n_in,
                              void* d_out, int out_size, void* d_ws, size_t ws_size,
                              hipStream_t stream) {
    const float* x     = (const float*)d_in[0];
    const float* pos   = (const float*)d_in[1];
    const int*   ei    = (const int*)d_in[2];
    const float* W1e   = (const float*)d_in[3];
    const float* b1e   = (const float*)d_in[4];
    const float* W2e   = (const float*)d_in[5];
    const float* b2e   = (const float*)d_in[6];
    const float* W1n   = (const float*)d_in[7];
    const float* b1n   = (const float*)d_in[8];
    const float* W2n   = (const float*)d_in[9];
    const float* b2n   = (const float*)d_in[10];
    const float* gamma = (const float*)d_in[11];
    const float* beta  = (const float*)d_in[12];
    float* out = (float*)d_out;

    // ws layout: Abf16 [N*D] | Bbf16 [N*D] | agg fp32 [N*D] | W2f bf16 [D*D]
    unsigned short* Abf = (unsigned short*)d_ws;
    unsigned short* Bbf = Abf + (size_t)NND * D;
    float*          agg = (float*)(Bbf + (size_t)NND * D);
    unsigned short* W2f = (unsigned short*)(agg + (size_t)NND * D);

    zero_kernel<<<2048, 256, 0, stream>>>((float4*)agg, NND * D / 4);
    w2f_kernel<<<(D * D) / 256, 256, 0, stream>>>(W2e, W2f);
    precompute_kernel<<<(NND + TN - 1) / TN, D, 0, stream>>>(x, W1e, Abf, Bbf);
    edge_kernel<<<NE / 64, 256, 0, stream>>>(Abf, Bbf, pos, ei, W1e, b1e,
                                             W2f, b2e, agg);
    node_kernel<<<(NND + TN - 1) / TN, D, 0, stream>>>(x, agg, W1n, b1n, W2n, b2n,
                                                       gamma, beta, out);
}